// Round 6
// baseline (1041.492 us; speedup 1.0000x reference)
//
#include <hip/hip_runtime.h>
#include <utility>

constexpr int G = 64;
constexpr int C = 16;
constexpr int NBATCH = 4;
constexpr int HID = 96;
constexpr int G3 = G * G * G; // 262144 = 2^18

// ---------------------------------------------------------------------------
// Pass 1: perception (edge-padded sobel stencil) + fused MLP + stochastic
// update.
//
// R6: kill the scratch demotion of p[64]. Evidence: R4 and R5 have identical
// ~725 MB WRITE_SIZE despite completely different weight paths -> the spill
// is p[64]+delta[16] (=80 floats = measured 320 B/thread excess writes).
// The per-channel staging loop (barriers + prefetch + tile[c&1] swap inside
// a #pragma unroll) was not cleanly unrolled, so p[c] became runtime-indexed
// -> whole array demoted to scratch (rule: dynamic-indexed arrays go to
// local memory). Fix: static_for<16> template expansion — every p index is
// a compile-time constant BY CONSTRUCTION; barriers/prefetch/buffer-swap
// become straight-line code.
// Keeps: per-channel double-buffered 9.6 KB tile (occupancy), wave-uniform
// scalar weight loads (zero VGPR cost, R1-proven), halo strides 12/120.
// One 8x8x8 voxel tile per block, 512 threads, 1 voxel/thread.
// ---------------------------------------------------------------------------
constexpr int SY = 12;           // halo row stride (2-way bank aliasing = free)
constexpr int SZ = 120;          // halo plane stride
constexpr int TILE_F = 10 * SZ;  // 1200 floats per channel buffer

template <typename F, int... I>
__device__ __forceinline__ void static_for_impl(F&& f, std::integer_sequence<int, I...>)
{
    (f(std::integral_constant<int, I>{}), ...);
}
template <int N, typename F>
__device__ __forceinline__ void static_for(F&& f)
{
    static_for_impl(static_cast<F&&>(f), std::make_integer_sequence<int, N>{});
}

__global__ __launch_bounds__(512)
void nca_update(const float* __restrict__ state, const float* __restrict__ rand_u,
                const float* __restrict__ w1, const float* __restrict__ b1,
                const float* __restrict__ w2,
                float* __restrict__ out, float* __restrict__ premask)
{
    __shared__ float tile[2][TILE_F]; // 9600 B total

    const int tid = threadIdx.x;
    const int bid = blockIdx.x;
    const int bx = bid & 7, by = (bid >> 3) & 7, bz = (bid >> 6) & 7, n = bid >> 9;
    const int x0 = bx * 8, y0 = by * 8, z0 = bz * 8;
    const float* sb = state + (size_t)n * C * G3;

    // --- halo source offsets + LDS targets (identical for every channel) ---
    const int i0 = tid;
    const int i1 = tid + 512;
    const bool wr1 = (i1 < 1000);
    int vo0, vo1, s0i, s1i;
    {
        int lx = i0 % 10, t = i0 / 10;
        int ly = t % 10, lz = t / 10;
        s0i = lz * SZ + ly * SY + lx;
        int gx = min(max(x0 + lx - 1, 0), G - 1);
        int gy = min(max(y0 + ly - 1, 0), G - 1);
        int gz = min(max(z0 + lz - 1, 0), G - 1);
        vo0 = gz * (G * G) + gy * G + gx;
    }
    {
        int j = min(i1, 999);
        int lx = j % 10, t = j / 10;
        int ly = t % 10, lz = t / 10;
        s1i = lz * SZ + ly * SY + lx;
        int gx = min(max(x0 + lx - 1, 0), G - 1);
        int gy = min(max(y0 + ly - 1, 0), G - 1);
        int gz = min(max(z0 + lz - 1, 0), G - 1);
        vo1 = gz * (G * G) + gy * G + gx;
    }

    // Per-voxel rand load issued early; consumed only at the end.
    const int lxl = (tid & 7) + 1, lyl = ((tid >> 3) & 7) + 1, lzl = (tid >> 6) + 1;
    const int gx = x0 + lxl - 1, gy = y0 + lyl - 1, gz = z0 + lzl - 1;
    const size_t vofs = (size_t)gz * (G * G) + (size_t)gy * G + gx;
    const float ru = rand_u[(size_t)n * G3 + vofs];

    // Stage channel 0.
    tile[0][s0i] = sb[vo0];
    if (wr1) tile[0][s1i] = sb[vo1];
    __syncthreads();

    const int cbase = (lzl - 1) * SZ + (lyl - 1) * SY + (lxl - 1);

    // Perception features; layout matches w1 columns: x = k*16 + c
    // (k: 0=identity, 1=sobel-z, 2=sobel-y, 3=sobel-x). All indices below
    // are compile-time constants -> p stays in registers (SROA-able).
    float p[64];
    float amax = -3.0e38f;

    static_for<C>([&](auto cc) {
        constexpr int c = decltype(cc)::value;

        // Prefetch next channel (HBM latency hides under the stencil).
        float r0 = 0.f, r1 = 0.f;
        if constexpr (c + 1 < C) {
            r0 = sb[(size_t)(c + 1) * G3 + vo0];
            r1 = sb[(size_t)(c + 1) * G3 + vo1];
        }

        const float* buf = tile[c & 1];
        float P0 = 0.f, P2 = 0.f, U0 = 0.f, U2 = 0.f, V0 = 0.f, V2 = 0.f;
        float ctr = 0.f, mx = -3.0e38f;
#pragma unroll
        for (int dz = 0; dz < 3; ++dz) {
            const float gzw = (dz == 1) ? 2.f : 1.f;
#pragma unroll
            for (int dy = 0; dy < 3; ++dy) {
                const float gyw = (dy == 1) ? 2.f : 1.f;
                const float* r = buf + cbase + dz * SZ + dy * SY;
                const float a0 = r[0], a1 = r[1], a2 = r[2];
                const float rs = a0 + 2.f * a1 + a2;
                if (dz == 0) P0 += gyw * rs;
                if (dz == 2) P2 += gyw * rs;
                if (dy == 0) U0 += gzw * rs;
                if (dy == 2) U2 += gzw * rs;
                V0 += gzw * gyw * a0;
                V2 += gzw * gyw * a2;
                if (dz == 1 && dy == 1) ctr = a1;
                if (c == 3) mx = fmaxf(mx, fmaxf(fmaxf(a0, a1), a2));
            }
        }
        if constexpr (c == 3) amax = mx;

        p[c]      = ctr;
        p[16 + c] = (P0 - P2) * 0.0625f;
        p[32 + c] = (U0 - U2) * 0.0625f;
        p[48 + c] = (V0 - V2) * 0.0625f;

        if constexpr (c + 1 < C) {
            float* nb = tile[(c + 1) & 1];
            nb[s0i] = r0;
            if (wr1) nb[s1i] = r1;
            __syncthreads();
        }
    });

    float delta[16];
    static_for<C>([&](auto cc) { delta[decltype(cc)::value] = 0.f; });

    // Fused MLP. All weight reads are wave-uniform -> batched s_load into the
    // SGPR file: zero VGPR pressure. p/delta indices all compile-time.
#pragma unroll 2
    for (int y = 0; y < HID; ++y) {
        const float* wr = w1 + y * 64;
        float h0 = b1[y], h1 = 0.f, h2 = 0.f, h3 = 0.f; // 4 chains, 16-deep each
        static_for<16>([&](auto jj) {
            constexpr int x = decltype(jj)::value * 4;
            h0 = fmaf(wr[x],     p[x],     h0);
            h1 = fmaf(wr[x + 1], p[x + 1], h1);
            h2 = fmaf(wr[x + 2], p[x + 2], h2);
            h3 = fmaf(wr[x + 3], p[x + 3], h3);
        });
        const float h = fmaxf((h0 + h1) + (h2 + h3), 0.f);
        static_for<C>([&](auto cc) {
            constexpr int c = decltype(cc)::value;
            delta[c] = fmaf(w2[c * HID + y], h, delta[c]);
        });
    }

    const float m = (ru < 0.5f) ? 1.f : 0.f;

    float* ob = out + (size_t)n * C * G3;
    static_for<C>([&](auto cc) {
        constexpr int c = decltype(cc)::value;
        // p[c] is the identity feature == old center value s0.
        ob[(size_t)c * G3 + vofs] = fmaf(delta[c], m, p[c]);
    });
    premask[(size_t)n * G3 + vofs] = (amax > 0.1f) ? 1.f : 0.f;
}

// ---------------------------------------------------------------------------
// Pass 2a: post-alive pooling on the NEW alpha (read-only on d_out),
// combine with pre-alive mask in-place in d_ws. No cross-thread hazards.
// ---------------------------------------------------------------------------
__global__ __launch_bounds__(256)
void nca_postmask(const float* __restrict__ newstate, float* __restrict__ mask)
{
    const int idx = blockIdx.x * 256 + threadIdx.x; // over NBATCH*G3
    const int n = idx >> 18;
    const int v = idx & (G3 - 1);
    const int x = v & 63, y = (v >> 6) & 63, z = v >> 12;
    const float* ab = newstate + ((size_t)n * C + 3) * G3;
    float mx = -3.0e38f;
#pragma unroll
    for (int dz = -1; dz <= 1; ++dz) {
        const int zz = min(max(z + dz, 0), G - 1);
#pragma unroll
        for (int dy = -1; dy <= 1; ++dy) {
            const int yy = min(max(y + dy, 0), G - 1);
            const int xm = max(x - 1, 0), xp = min(x + 1, G - 1);
            const float* row = ab + (size_t)zz * (G * G) + (size_t)yy * G;
            mx = fmaxf(mx, fmaxf(fmaxf(row[xm], row[x]), row[xp]));
        }
    }
    const float post = (mx > 0.1f) ? 1.f : 0.f;
    mask[idx] *= post;
}

// ---------------------------------------------------------------------------
// Pass 2b: out *= mask (broadcast over channels), float4-vectorized.
// ---------------------------------------------------------------------------
__global__ __launch_bounds__(256)
void nca_apply(float4* __restrict__ out4, const float4* __restrict__ mask4)
{
    const int idx = blockIdx.x * 256 + threadIdx.x; // over NBATCH*C*G3/4
    const size_t base = (size_t)idx * 4;
    const int n = (int)(base >> 22);          // C*G3 = 2^22
    const int v = (int)(base & (G3 - 1));     // G3 = 2^18
    const float4 m = mask4[((size_t)n * G3 + v) >> 2];
    float4 o = out4[idx];
    o.x *= m.x; o.y *= m.y; o.z *= m.z; o.w *= m.w;
    out4[idx] = o;
}

extern "C" void kernel_launch(void* const* d_in, const int* in_sizes, int n_in,
                              void* d_out, int out_size, void* d_ws, size_t ws_size,
                              hipStream_t stream)
{
    const float* state  = (const float*)d_in[0];
    const float* rand_u = (const float*)d_in[1];
    const float* w1     = (const float*)d_in[2];
    const float* b1     = (const float*)d_in[3];
    const float* w2     = (const float*)d_in[4];
    float* out  = (float*)d_out;
    float* mask = (float*)d_ws; // NBATCH*G3 floats = 4 MiB scratch

    nca_update  <<<NBATCH * 8 * 8 * 8, 512, 0, stream>>>(state, rand_u, w1, b1, w2, out, mask);
    nca_postmask<<<(NBATCH * G3) / 256, 256, 0, stream>>>(out, mask);
    nca_apply   <<<(NBATCH * C * G3 / 4) / 256, 256, 0, stream>>>((float4*)out, (const float4*)mask);
}

// Round 7
// 707.564 us; speedup vs baseline: 1.4719x; 1.4719x over previous
//
#include <hip/hip_runtime.h>

constexpr int G = 64;
constexpr int C = 16;
constexpr int NBATCH = 4;
constexpr int HID = 96;
constexpr int G3 = G * G * G; // 262144 = 2^18

// ---------------------------------------------------------------------------
// Pass 1: perception (edge-padded sobel stencil) + fused MLP + stochastic
// update.
//
// R7: back to R1's proven zero-spill SHAPE (bulk load -> barrier -> stencil;
// no global loads / barriers interleaved with the stencil), with the LDS cut
// from 64 KB to 37.5 KB by staging 8 channels per group (2 groups, 3
// barriers). Evidence trail:
//  - R1 (monolithic): 84 VGPR, FETCH 179 MB / WRITE 69.6 MB = ideal, zero
//    spill; limited only by 64 KB LDS -> 1 block/CU (24% occupancy).
//  - R2..R6 (per-channel double-buffer + prefetch): all carry scratch spill
//    signature (WRITE 454-729 MB, 6-10x ideal). The prefetch regs + hoisted
//    future-channel addresses + growing p[] overflow the allocator's 128
//    budget; static_for (R6) proved it is NOT an indexing artifact.
// 8-channel groups: tile[8][1200] = 37.5 KB -> 2 blocks/CU (VGPR-limited,
// ~16 waves/CU = ~50% occupancy, 2x R1).
// One 8x8x8 voxel tile per block, 512 threads, 1 voxel/thread.
// ---------------------------------------------------------------------------
constexpr int SY = 12;           // halo row stride
constexpr int SZ = 120;          // halo plane stride
constexpr int TILE_F = 10 * SZ;  // 1200 floats per channel

__global__ __launch_bounds__(512)
void nca_update(const float* __restrict__ state, const float* __restrict__ rand_u,
                const float* __restrict__ w1, const float* __restrict__ b1,
                const float* __restrict__ w2,
                float* __restrict__ out, float* __restrict__ premask)
{
    __shared__ float tile[8][TILE_F]; // 38400 B

    const int tid = threadIdx.x;
    const int bid = blockIdx.x;
    const int bx = bid & 7, by = (bid >> 3) & 7, bz = (bid >> 6) & 7, n = bid >> 9;
    const int x0 = bx * 8, y0 = by * 8, z0 = bz * 8;
    const float* sb = state + (size_t)n * C * G3;

    // --- halo source offsets + LDS targets (identical for every channel) ---
    const int i0 = tid;
    const int i1 = tid + 512;
    const bool wr1 = (i1 < 1000);
    int vo0, vo1, s0i, s1i;
    {
        int lx = i0 % 10, t = i0 / 10;
        int ly = t % 10, lz = t / 10;
        s0i = lz * SZ + ly * SY + lx;
        int gx = min(max(x0 + lx - 1, 0), G - 1);
        int gy = min(max(y0 + ly - 1, 0), G - 1);
        int gz = min(max(z0 + lz - 1, 0), G - 1);
        vo0 = gz * (G * G) + gy * G + gx;
    }
    {
        int j = min(i1, 999);
        int lx = j % 10, t = j / 10;
        int ly = t % 10, lz = t / 10;
        s1i = lz * SZ + ly * SY + lx;
        int gx = min(max(x0 + lx - 1, 0), G - 1);
        int gy = min(max(y0 + ly - 1, 0), G - 1);
        int gz = min(max(z0 + lz - 1, 0), G - 1);
        vo1 = gz * (G * G) + gy * G + gx;
    }

    // Per-voxel rand load issued early; consumed only at the end.
    const int lxl = (tid & 7) + 1, lyl = ((tid >> 3) & 7) + 1, lzl = (tid >> 6) + 1;
    const int gx = x0 + lxl - 1, gy = y0 + lyl - 1, gz = z0 + lzl - 1;
    const size_t vofs = (size_t)gz * (G * G) + (size_t)gy * G + gx;
    const float ru = rand_u[(size_t)n * G3 + vofs];

    const int cbase = (lzl - 1) * SZ + (lyl - 1) * SY + (lxl - 1);

    // Perception features; layout matches w1 columns: x = k*16 + c
    // (k: 0=identity, 1=sobel-z, 2=sobel-y, 3=sobel-x).
    float p[64];
    float amax = -3.0e38f;

#pragma unroll
    for (int g = 0; g < 2; ++g) {
        const float* sg = sb + (size_t)(g * 8) * G3;

        if (g) __syncthreads(); // previous group's stencil reads done (WAR)

        // Bulk-load 8 channels: 16 coalesced loads, nothing lives past the
        // barrier in registers (R1's zero-spill pattern).
#pragma unroll
        for (int c = 0; c < 8; ++c) {
            tile[c][s0i] = sg[(size_t)c * G3 + vo0];
            if (wr1) tile[c][s1i] = sg[(size_t)c * G3 + vo1];
        }
        __syncthreads();

#pragma unroll
        for (int c = 0; c < 8; ++c) {
            const int cg = g * 8 + c;
            const float* buf = tile[c];
            float P0 = 0.f, P2 = 0.f, U0 = 0.f, U2 = 0.f, V0 = 0.f, V2 = 0.f;
            float ctr = 0.f, mx = -3.0e38f;
#pragma unroll
            for (int dz = 0; dz < 3; ++dz) {
                const float gzw = (dz == 1) ? 2.f : 1.f;
#pragma unroll
                for (int dy = 0; dy < 3; ++dy) {
                    const float gyw = (dy == 1) ? 2.f : 1.f;
                    const float* r = buf + cbase + dz * SZ + dy * SY;
                    const float a0 = r[0], a1 = r[1], a2 = r[2];
                    const float rs = a0 + 2.f * a1 + a2;
                    if (dz == 0) P0 += gyw * rs;
                    if (dz == 2) P2 += gyw * rs;
                    if (dy == 0) U0 += gzw * rs;
                    if (dy == 2) U2 += gzw * rs;
                    V0 += gzw * gyw * a0;
                    V2 += gzw * gyw * a2;
                    if (dz == 1 && dy == 1) ctr = a1;
                    if (cg == 3) mx = fmaxf(mx, fmaxf(fmaxf(a0, a1), a2));
                }
            }
            if (cg == 3) amax = mx;

            p[cg]      = ctr;
            p[16 + cg] = (P0 - P2) * 0.0625f;
            p[32 + cg] = (U0 - U2) * 0.0625f;
            p[48 + cg] = (V0 - V2) * 0.0625f;
        }
    }

    float delta[C];
#pragma unroll
    for (int c = 0; c < C; ++c) delta[c] = 0.f;

    // Fused MLP. All weight reads are wave-uniform -> batched s_load into the
    // SGPR file: zero VGPR pressure (R1-proven form, bit-identical order).
#pragma unroll 2
    for (int y = 0; y < HID; ++y) {
        const float* wr = w1 + y * 64;
        float h0 = b1[y], h1 = 0.f, h2 = 0.f, h3 = 0.f; // 4 chains, 16-deep each
#pragma unroll
        for (int x = 0; x < 64; x += 4) {
            h0 = fmaf(wr[x],     p[x],     h0);
            h1 = fmaf(wr[x + 1], p[x + 1], h1);
            h2 = fmaf(wr[x + 2], p[x + 2], h2);
            h3 = fmaf(wr[x + 3], p[x + 3], h3);
        }
        const float h = fmaxf((h0 + h1) + (h2 + h3), 0.f);
#pragma unroll
        for (int c = 0; c < C; ++c) delta[c] = fmaf(w2[c * HID + y], h, delta[c]);
    }

    const float m = (ru < 0.5f) ? 1.f : 0.f;

    float* ob = out + (size_t)n * C * G3;
#pragma unroll
    for (int c = 0; c < C; ++c) {
        // p[c] is the identity feature == old center value s0.
        ob[(size_t)c * G3 + vofs] = fmaf(delta[c], m, p[c]);
    }
    premask[(size_t)n * G3 + vofs] = (amax > 0.1f) ? 1.f : 0.f;
}

// ---------------------------------------------------------------------------
// Pass 2a: post-alive pooling on the NEW alpha (read-only on d_out),
// combine with pre-alive mask in-place in d_ws. No cross-thread hazards.
// ---------------------------------------------------------------------------
__global__ __launch_bounds__(256)
void nca_postmask(const float* __restrict__ newstate, float* __restrict__ mask)
{
    const int idx = blockIdx.x * 256 + threadIdx.x; // over NBATCH*G3
    const int n = idx >> 18;
    const int v = idx & (G3 - 1);
    const int x = v & 63, y = (v >> 6) & 63, z = v >> 12;
    const float* ab = newstate + ((size_t)n * C + 3) * G3;
    float mx = -3.0e38f;
#pragma unroll
    for (int dz = -1; dz <= 1; ++dz) {
        const int zz = min(max(z + dz, 0), G - 1);
#pragma unroll
        for (int dy = -1; dy <= 1; ++dy) {
            const int yy = min(max(y + dy, 0), G - 1);
            const int xm = max(x - 1, 0), xp = min(x + 1, G - 1);
            const float* row = ab + (size_t)zz * (G * G) + (size_t)yy * G;
            mx = fmaxf(mx, fmaxf(fmaxf(row[xm], row[x]), row[xp]));
        }
    }
    const float post = (mx > 0.1f) ? 1.f : 0.f;
    mask[idx] *= post;
}

// ---------------------------------------------------------------------------
// Pass 2b: out *= mask (broadcast over channels), float4-vectorized.
// ---------------------------------------------------------------------------
__global__ __launch_bounds__(256)
void nca_apply(float4* __restrict__ out4, const float4* __restrict__ mask4)
{
    const int idx = blockIdx.x * 256 + threadIdx.x; // over NBATCH*C*G3/4
    const size_t base = (size_t)idx * 4;
    const int n = (int)(base >> 22);          // C*G3 = 2^22
    const int v = (int)(base & (G3 - 1));     // G3 = 2^18
    const float4 m = mask4[((size_t)n * G3 + v) >> 2];
    float4 o = out4[idx];
    o.x *= m.x; o.y *= m.y; o.z *= m.z; o.w *= m.w;
    out4[idx] = o;
}

extern "C" void kernel_launch(void* const* d_in, const int* in_sizes, int n_in,
                              void* d_out, int out_size, void* d_ws, size_t ws_size,
                              hipStream_t stream)
{
    const float* state  = (const float*)d_in[0];
    const float* rand_u = (const float*)d_in[1];
    const float* w1     = (const float*)d_in[2];
    const float* b1     = (const float*)d_in[3];
    const float* w2     = (const float*)d_in[4];
    float* out  = (float*)d_out;
    float* mask = (float*)d_ws; // NBATCH*G3 floats = 4 MiB scratch

    nca_update  <<<NBATCH * 8 * 8 * 8, 512, 0, stream>>>(state, rand_u, w1, b1, w2, out, mask);
    nca_postmask<<<(NBATCH * G3) / 256, 256, 0, stream>>>(out, mask);
    nca_apply   <<<(NBATCH * C * G3 / 4) / 256, 256, 0, stream>>>((float4*)out, (const float4*)mask);
}

// Round 8
// 328.745 us; speedup vs baseline: 3.1681x; 2.1523x over previous
//
#include <hip/hip_runtime.h>

constexpr int G = 64;
constexpr int C = 16;
constexpr int NBATCH = 4;
constexpr int HID = 96;
constexpr int G3 = G * G * G; // 262144 = 2^18

typedef _Float16 h2 __attribute__((ext_vector_type(2)));

#if __has_builtin(__builtin_amdgcn_fdot2)
__device__ __forceinline__ float fdot2(h2 a, h2 b, float c) {
    return __builtin_amdgcn_fdot2(a, b, c, false);
}
#else
__device__ __forceinline__ float fdot2(h2 a, h2 b, float c) {
    return c + (float)a.x * (float)b.x + (float)a.y * (float)b.y;
}
#endif

// ---------------------------------------------------------------------------
// Pass 0: pack w1 (96x64) and w2 (16x96) to f16 pairs.
//   w1p[y*32+j] = (w1[y,2j], w1[y,2j+1])          -> 3072 h2 = 12 KB
//   w2p[yp*16+c] = (w2[c,2yp], w2[c,2yp+1])       ->  768 h2 =  3 KB
// Total packed weights + b1 = 15.7 KB: FITS the 16 KB per-CU scalar K$.
// That is the point: R7's MLP stalled ~200 cyc per row because w1 (24.6 KB
// fp32) missed K$ to L2 on every pass, and SMEM loads force lgkmcnt(0)
// drains (no partial counting) so the latency was fully exposed.
// ---------------------------------------------------------------------------
__global__ __launch_bounds__(256)
void nca_packw(const float* __restrict__ w1, const float* __restrict__ w2,
               h2* __restrict__ w1p, h2* __restrict__ w2p)
{
    const int i = blockIdx.x * 256 + threadIdx.x;
    if (i < HID * 32) { // w1 pairs are within a row (64 even)
        h2 v; v.x = (_Float16)w1[2 * i]; v.y = (_Float16)w1[2 * i + 1];
        w1p[i] = v;
    }
    if (i < 48 * 16) {
        const int yp = i >> 4, c = i & 15;
        h2 v; v.x = (_Float16)w2[c * HID + 2 * yp]; v.y = (_Float16)w2[c * HID + 2 * yp + 1];
        w2p[i] = v;
    }
}

// ---------------------------------------------------------------------------
// Pass 1: perception (edge-padded sobel stencil) + fused MLP + stochastic
// update.
//
// R8: f16-packed MLP on top of R7's proven zero-spill structure.
//  - Stencil identical to R7 (8-channel bulk groups, strides 12/120,
//    FETCH 179 MB / WRITE 69.6 MB = ideal, zero scratch).
//  - Perception features packed to h2 pp[32] as they are produced (fp32
//    centers kept in ctrf[16] so the state passthrough stays exact).
//  - MLP: per y-pair, two w1 rows (32 h2 each, wave-uniform s_load, K$-hit)
//    feed 8 independent v_dot2_f32_f16 chains; h pair packed to h2 and
//    folded into delta[16] via w2p. Weights live in SGPRs: zero VGPR cost.
// One 8x8x8 voxel tile per block, 512 threads, 1 voxel/thread.
// ---------------------------------------------------------------------------
constexpr int SY = 12;           // halo row stride
constexpr int SZ = 120;          // halo plane stride
constexpr int TILE_F = 10 * SZ;  // 1200 floats per channel

__global__ __launch_bounds__(512)
void nca_update(const float* __restrict__ state, const float* __restrict__ rand_u,
                const h2* __restrict__ w1p, const float* __restrict__ b1,
                const h2* __restrict__ w2p,
                float* __restrict__ out, float* __restrict__ premask)
{
    __shared__ float tile[8][TILE_F]; // 38400 B

    const int tid = threadIdx.x;
    const int bid = blockIdx.x;
    const int bx = bid & 7, by = (bid >> 3) & 7, bz = (bid >> 6) & 7, n = bid >> 9;
    const int x0 = bx * 8, y0 = by * 8, z0 = bz * 8;
    const float* sb = state + (size_t)n * C * G3;

    // --- halo source offsets + LDS targets (identical for every channel) ---
    const int i0 = tid;
    const int i1 = tid + 512;
    const bool wr1 = (i1 < 1000);
    int vo0, vo1, s0i, s1i;
    {
        int lx = i0 % 10, t = i0 / 10;
        int ly = t % 10, lz = t / 10;
        s0i = lz * SZ + ly * SY + lx;
        int gx = min(max(x0 + lx - 1, 0), G - 1);
        int gy = min(max(y0 + ly - 1, 0), G - 1);
        int gz = min(max(z0 + lz - 1, 0), G - 1);
        vo0 = gz * (G * G) + gy * G + gx;
    }
    {
        int j = min(i1, 999);
        int lx = j % 10, t = j / 10;
        int ly = t % 10, lz = t / 10;
        s1i = lz * SZ + ly * SY + lx;
        int gx = min(max(x0 + lx - 1, 0), G - 1);
        int gy = min(max(y0 + ly - 1, 0), G - 1);
        int gz = min(max(z0 + lz - 1, 0), G - 1);
        vo1 = gz * (G * G) + gy * G + gx;
    }

    // Per-voxel rand load issued early; consumed only at the end.
    const int lxl = (tid & 7) + 1, lyl = ((tid >> 3) & 7) + 1, lzl = (tid >> 6) + 1;
    const int gx = x0 + lxl - 1, gy = y0 + lyl - 1, gz = z0 + lzl - 1;
    const size_t vofs = (size_t)gz * (G * G) + (size_t)gy * G + gx;
    const float ru = rand_u[(size_t)n * G3 + vofs];

    const int cbase = (lzl - 1) * SZ + (lyl - 1) * SY + (lxl - 1);

    // Packed perception features: pair j <-> features (2j, 2j+1), feature
    // x = k*16 + c, so pp[k*8 + c/2] pairs channels (c, c+1) of kernel k.
    h2 pp[32];
    float ctrf[C];          // exact fp32 centers for the state passthrough
    float pf0 = 0.f, pf1 = 0.f, pf2 = 0.f, pf3 = 0.f; // even-channel carry
    float amax = -3.0e38f;

#pragma unroll
    for (int g = 0; g < 2; ++g) {
        const float* sg = sb + (size_t)(g * 8) * G3;

        if (g) __syncthreads(); // previous group's stencil reads done (WAR)

        // Bulk-load 8 channels (R1/R7's zero-spill pattern).
#pragma unroll
        for (int c = 0; c < 8; ++c) {
            tile[c][s0i] = sg[(size_t)c * G3 + vo0];
            if (wr1) tile[c][s1i] = sg[(size_t)c * G3 + vo1];
        }
        __syncthreads();

#pragma unroll
        for (int c = 0; c < 8; ++c) {
            const int cg = g * 8 + c;
            const float* buf = tile[c];
            float P0 = 0.f, P2 = 0.f, U0 = 0.f, U2 = 0.f, V0 = 0.f, V2 = 0.f;
            float ctr = 0.f, mx = -3.0e38f;
#pragma unroll
            for (int dz = 0; dz < 3; ++dz) {
                const float gzw = (dz == 1) ? 2.f : 1.f;
#pragma unroll
                for (int dy = 0; dy < 3; ++dy) {
                    const float gyw = (dy == 1) ? 2.f : 1.f;
                    const float* r = buf + cbase + dz * SZ + dy * SY;
                    const float a0 = r[0], a1 = r[1], a2 = r[2];
                    const float rs = a0 + 2.f * a1 + a2;
                    if (dz == 0) P0 += gyw * rs;
                    if (dz == 2) P2 += gyw * rs;
                    if (dy == 0) U0 += gzw * rs;
                    if (dy == 2) U2 += gzw * rs;
                    V0 += gzw * gyw * a0;
                    V2 += gzw * gyw * a2;
                    if (dz == 1 && dy == 1) ctr = a1;
                    if (cg == 3) mx = fmaxf(mx, fmaxf(fmaxf(a0, a1), a2));
                }
            }
            if (cg == 3) amax = mx;

            const float f0 = ctr;
            const float f1 = (P0 - P2) * 0.0625f;
            const float f2 = (U0 - U2) * 0.0625f;
            const float f3 = (V0 - V2) * 0.0625f;
            ctrf[cg] = ctr;

            if (cg & 1) {
                const int j = cg >> 1;
                h2 v;
                v.x = (_Float16)pf0; v.y = (_Float16)f0; pp[j]      = v;
                v.x = (_Float16)pf1; v.y = (_Float16)f1; pp[8 + j]  = v;
                v.x = (_Float16)pf2; v.y = (_Float16)f2; pp[16 + j] = v;
                v.x = (_Float16)pf3; v.y = (_Float16)f3; pp[24 + j] = v;
            } else {
                pf0 = f0; pf1 = f1; pf2 = f2; pf3 = f3;
            }
        }
    }

    float delta[C];
#pragma unroll
    for (int c = 0; c < C; ++c) delta[c] = 0.f;

    // Fused MLP over y-pairs. Weight reads are wave-uniform s_loads from the
    // 15.7 KB packed block (K$-resident). 8 independent dot2 chains.
#pragma unroll 2
    for (int yp = 0; yp < 48; ++yp) {
        const h2* r0 = w1p + (2 * yp) * 32;
        const h2* r1 = r0 + 32;
        float a0 = 0.f, a1 = 0.f, a2 = 0.f, a3 = 0.f;
        float c0 = 0.f, c1 = 0.f, c2 = 0.f, c3 = 0.f;
#pragma unroll
        for (int j = 0; j < 32; j += 4) {
            a0 = fdot2(r0[j],     pp[j],     a0);
            a1 = fdot2(r0[j + 1], pp[j + 1], a1);
            a2 = fdot2(r0[j + 2], pp[j + 2], a2);
            a3 = fdot2(r0[j + 3], pp[j + 3], a3);
            c0 = fdot2(r1[j],     pp[j],     c0);
            c1 = fdot2(r1[j + 1], pp[j + 1], c1);
            c2 = fdot2(r1[j + 2], pp[j + 2], c2);
            c3 = fdot2(r1[j + 3], pp[j + 3], c3);
        }
        const float ha = fmaxf(b1[2 * yp]     + ((a0 + a1) + (a2 + a3)), 0.f);
        const float hb = fmaxf(b1[2 * yp + 1] + ((c0 + c1) + (c2 + c3)), 0.f);
        h2 hh; hh.x = (_Float16)ha; hh.y = (_Float16)hb;
        const h2* w2r = w2p + yp * 16;
#pragma unroll
        for (int c = 0; c < C; ++c) delta[c] = fdot2(w2r[c], hh, delta[c]);
    }

    const float m = (ru < 0.5f) ? 1.f : 0.f;

    float* ob = out + (size_t)n * C * G3;
#pragma unroll
    for (int c = 0; c < C; ++c) {
        ob[(size_t)c * G3 + vofs] = fmaf(delta[c], m, ctrf[c]); // exact s0
    }
    premask[(size_t)n * G3 + vofs] = (amax > 0.1f) ? 1.f : 0.f;
}

// ---------------------------------------------------------------------------
// Pass 2a: post-alive pooling on the NEW alpha (read-only on d_out),
// combine with pre-alive mask in-place in d_ws. No cross-thread hazards.
// ---------------------------------------------------------------------------
__global__ __launch_bounds__(256)
void nca_postmask(const float* __restrict__ newstate, float* __restrict__ mask)
{
    const int idx = blockIdx.x * 256 + threadIdx.x; // over NBATCH*G3
    const int n = idx >> 18;
    const int v = idx & (G3 - 1);
    const int x = v & 63, y = (v >> 6) & 63, z = v >> 12;
    const float* ab = newstate + ((size_t)n * C + 3) * G3;
    float mx = -3.0e38f;
#pragma unroll
    for (int dz = -1; dz <= 1; ++dz) {
        const int zz = min(max(z + dz, 0), G - 1);
#pragma unroll
        for (int dy = -1; dy <= 1; ++dy) {
            const int yy = min(max(y + dy, 0), G - 1);
            const int xm = max(x - 1, 0), xp = min(x + 1, G - 1);
            const float* row = ab + (size_t)zz * (G * G) + (size_t)yy * G;
            mx = fmaxf(mx, fmaxf(fmaxf(row[xm], row[x]), row[xp]));
        }
    }
    const float post = (mx > 0.1f) ? 1.f : 0.f;
    mask[idx] *= post;
}

// ---------------------------------------------------------------------------
// Pass 2b: out *= mask (broadcast over channels), float4-vectorized.
// ---------------------------------------------------------------------------
__global__ __launch_bounds__(256)
void nca_apply(float4* __restrict__ out4, const float4* __restrict__ mask4)
{
    const int idx = blockIdx.x * 256 + threadIdx.x; // over NBATCH*C*G3/4
    const size_t base = (size_t)idx * 4;
    const int n = (int)(base >> 22);          // C*G3 = 2^22
    const int v = (int)(base & (G3 - 1));     // G3 = 2^18
    const float4 m = mask4[((size_t)n * G3 + v) >> 2];
    float4 o = out4[idx];
    o.x *= m.x; o.y *= m.y; o.z *= m.z; o.w *= m.w;
    out4[idx] = o;
}

extern "C" void kernel_launch(void* const* d_in, const int* in_sizes, int n_in,
                              void* d_out, int out_size, void* d_ws, size_t ws_size,
                              hipStream_t stream)
{
    const float* state  = (const float*)d_in[0];
    const float* rand_u = (const float*)d_in[1];
    const float* w1     = (const float*)d_in[2];
    const float* b1     = (const float*)d_in[3];
    const float* w2     = (const float*)d_in[4];
    float* out  = (float*)d_out;

    // Workspace layout: [0,12KB) w1p, [12KB,15KB) w2p, [16KB, 16KB+4MiB) mask.
    h2*    w1p  = (h2*)d_ws;
    h2*    w2p  = (h2*)((char*)d_ws + 12 * 1024);
    float* mask = (float*)((char*)d_ws + 16 * 1024);

    nca_packw   <<<12, 256, 0, stream>>>(w1, w2, w1p, w2p);
    nca_update  <<<NBATCH * 8 * 8 * 8, 512, 0, stream>>>(state, rand_u, w1p, b1, w2p, out, mask);
    nca_postmask<<<(NBATCH * G3) / 256, 256, 0, stream>>>(out, mask);
    nca_apply   <<<(NBATCH * C * G3 / 4) / 256, 256, 0, stream>>>((float4*)out, (const float4*)mask);
}